// Round 3
// baseline (565.402 us; speedup 1.0000x reference)
//
#include <hip/hip_runtime.h>
#include <math.h>

// Branchless, static-indexed rewrite of the bit-faithful f32 reference
// replication. Round-2 lesson: math is ~1.5k VALU ops/thread but measured
// ~16k — dynamic-indexed private arrays (append compaction + insertion
// sort) compile to cndmask chains / divergent serialized loops. Fix:
// 24 static slots with mask bits (mirrors the reference's own masked-slot
// formulation), Batcher merge-exchange network sort (127 CEs, all static
// indices), pseudo-angle sort key (monotone in atan2 -> same cyclic order
// except area-continuous 1-ulp ties). All mask-deciding arithmetic
// (__f*_rn chains, OCML atan2f/cosf/sinf) bit-identical to round 2.

#define FMUL __fmul_rn
#define FADD __fadd_rn
#define FSUB __fsub_rn
#define FDIV __fdiv_rn

__global__ __launch_bounds__(256)
void riou_kernel(const float* __restrict__ pred,
                 const float* __restrict__ tgt,
                 float* __restrict__ out, int n)
{
    int i = blockIdx.x * blockDim.x + threadIdx.x;
    if (i >= n) return;

    const float* p = pred + 6 * (size_t)i;
    const float* q = tgt  + 6 * (size_t)i;

    const float px = p[0], py = p[1], pw = p[2], ph = p[3];
    const float qx = q[0], qy = q[1], qw = q[2], qh = q[3];

    // bit-critical transcendental sequence (matches jax-rocm lowering)
    float rad1 = atan2f(p[4], p[5]);
    float cA = cosf(rad1), sA = sinf(rad1);
    float rad2 = atan2f(q[4], q[5]);
    float cB = cosf(rad2), sB = sinf(rad2);

    const float ddx[4] = {0.5f, -0.5f, -0.5f, 0.5f};
    const float ddy[4] = {0.5f, 0.5f, -0.5f, -0.5f};
    float c1x[4], c1y[4], c2x[4], c2y[4];
#pragma unroll
    for (int j = 0; j < 4; j++) {
        float cx = FMUL(ddx[j], pw), cy = FMUL(ddy[j], ph);
        c1x[j] = FADD(FSUB(FMUL(cx, cA), FMUL(cy, sA)), px);
        c1y[j] = FADD(FADD(FMUL(cx, sA), FMUL(cy, cA)), py);
        float dx2 = FMUL(ddx[j], qw), dy2 = FMUL(ddy[j], qh);
        c2x[j] = FADD(FSUB(FMUL(dx2, cB), FMUL(dy2, sB)), qx);
        c2y[j] = FADD(FADD(FMUL(dx2, sB), FMUL(dy2, cB)), qy);
    }

    // enclosing-box diagonal now (frees corner liveness later)
    float minx = c1x[0], maxx = c1x[0], miny = c1y[0], maxy = c1y[0];
#pragma unroll
    for (int j = 1; j < 4; j++) {
        minx = fminf(minx, c1x[j]); maxx = fmaxf(maxx, c1x[j]);
        miny = fminf(miny, c1y[j]); maxy = fmaxf(maxy, c1y[j]);
    }
#pragma unroll
    for (int j = 0; j < 4; j++) {
        minx = fminf(minx, c2x[j]); maxx = fmaxf(maxx, c2x[j]);
        miny = fminf(miny, c2y[j]); maxy = fmaxf(maxy, c2y[j]);
    }
    float wc = FSUB(maxx, minx), hc = FSUB(maxy, miny);
    float c2d = FADD(FMUL(wc, wc), FMUL(hc, hc));
    float dxc = FSUB(px, qx), dyc = FSUB(py, qy);
    float d2 = FADD(FMUL(dxc, dxc), FMUL(dyc, dyc));

    // ---- static 24-slot vertex table ----
    float vx[24], vy[24];
    unsigned mbits = 0;
    int k = 0;
    float sx = 0.0f, sy = 0.0f;

    const float eps = 1e-6f;
    const float hieps = 1.0f + 1e-6f;

    // slots 0-3: c1 corners inside c2
    {
        float ax = c2x[0], ay = c2y[0];
        float abx = FSUB(c2x[1], ax), aby = FSUB(c2y[1], ay);
        float adx = FSUB(c2x[3], ax), ady = FSUB(c2y[3], ay);
        float dab = FADD(FMUL(abx, abx), FMUL(aby, aby));
        float dad = FADD(FMUL(adx, adx), FMUL(ady, ady));
#pragma unroll
        for (int j = 0; j < 4; j++) {
            float amx = FSUB(c1x[j], ax), amy = FSUB(c1y[j], ay);
            float pab = FDIV(FADD(FMUL(abx, amx), FMUL(aby, amy)), dab);
            float pad = FDIV(FADD(FMUL(adx, amx), FMUL(ady, amy)), dad);
            int m = (pab > -eps) & (pab < hieps) & (pad > -eps) & (pad < hieps);
            vx[j] = c1x[j]; vy[j] = c1y[j];
            mbits |= (unsigned)m << j;
            k += m;
            sx = FADD(sx, m ? c1x[j] : 0.0f);
            sy = FADD(sy, m ? c1y[j] : 0.0f);
        }
    }
    // slots 4-7: c2 corners inside c1
    {
        float ax = c1x[0], ay = c1y[0];
        float abx = FSUB(c1x[1], ax), aby = FSUB(c1y[1], ay);
        float adx = FSUB(c1x[3], ax), ady = FSUB(c1y[3], ay);
        float dab = FADD(FMUL(abx, abx), FMUL(aby, aby));
        float dad = FADD(FMUL(adx, adx), FMUL(ady, ady));
#pragma unroll
        for (int j = 0; j < 4; j++) {
            float amx = FSUB(c2x[j], ax), amy = FSUB(c2y[j], ay);
            float pab = FDIV(FADD(FMUL(abx, amx), FMUL(aby, amy)), dab);
            float pad = FDIV(FADD(FMUL(adx, amx), FMUL(ady, amy)), dad);
            int m = (pab > -eps) & (pab < hieps) & (pad > -eps) & (pad < hieps);
            vx[4 + j] = c2x[j]; vy[4 + j] = c2y[j];
            mbits |= (unsigned)m << (4 + j);
            k += m;
            sx = FADD(sx, m ? c2x[j] : 0.0f);
            sy = FADD(sy, m ? c2y[j] : 0.0f);
        }
    }
    // slots 8-23: edge intersections, slot = 8 + 4*e1 + e2 (ref reshape order)
#pragma unroll
    for (int e1 = 0; e1 < 4; e1++) {
        float x1 = c1x[e1], y1 = c1y[e1];
        float x2 = c1x[(e1 + 1) & 3], y2 = c1y[(e1 + 1) & 3];
        float ex = FSUB(x2, x1), ey = FSUB(y2, y1);
#pragma unroll
        for (int e2 = 0; e2 < 4; e2++) {
            float x3 = c2x[e2], y3 = c2y[e2];
            float x4 = c2x[(e2 + 1) & 3], y4 = c2y[(e2 + 1) & 3];
            float num_t = FSUB(FMUL(ex, FSUB(y3, y1)), FMUL(ey, FSUB(x3, x1)));
            float den_t = FSUB(FMUL(ex, FSUB(y3, y4)), FMUL(ey, FSUB(x3, x4)));
            float tq = FDIV(num_t, den_t);   // den==0 -> inf/nan -> masked out
            float fx = FSUB(x4, x3), fy = FSUB(y4, y3);
            float num_u = FSUB(FMUL(fx, FSUB(y1, y3)), FMUL(fy, FSUB(x1, x3)));
            float den_u = FSUB(FMUL(fx, FSUB(y1, y2)), FMUL(fy, FSUB(x1, x2)));
            float uq = FDIV(num_u, den_u);
            int m = (tq > 0.0f) & (tq < 1.0f) & (uq > 0.0f) & (uq < 1.0f);
            float ix = FADD(x1, FMUL(tq, ex));   // garbage if masked; gated
            float iy = FADD(y1, FMUL(tq, ey));
            int s = 8 + 4 * e1 + e2;
            vx[s] = ix; vy[s] = iy;
            mbits |= (unsigned)m << s;
            k += m;
            sx = FADD(sx, m ? ix : 0.0f);
            sy = FADD(sy, m ? iy : 0.0f);
        }
    }

    // centroid (f32 div, max(k,1))
    float kk = (float)(k > 0 ? k : 1);
    float mx = FDIV(sx, kk), my = FDIV(sy, kk);

    // recenter + pseudo-angle keys (monotone in atan2; masked -> 1e9, v=0)
    float ang[24];
#pragma unroll
    for (int j = 0; j < 24; j++) {
        int m = (mbits >> j) & 1u;
        float wx2 = m ? FSUB(vx[j], mx) : 0.0f;
        float wy2 = m ? FSUB(vy[j], my) : 0.0f;
        vx[j] = wx2; vy[j] = wy2;
        float dsum = FADD(fabsf(wx2), fabsf(wy2));
        float rs = (dsum > 0.0f) ? FMUL(wx2, __builtin_amdgcn_rcpf(dsum)) : 1.0f;
        float key = copysignf(FSUB(1.0f, rs), wy2);   // (-2,2], increasing in angle
        ang[j] = m ? key : 1e9f;
    }

    // Batcher merge-exchange sort network, n=24 (Knuth 5.2.2M), 127 CEs.
    // Passes (p,d,r); CE(i,i+d) for i+d<24 && (i&p)==r. All static indices.
    const int P3[15][3] = {
        {16,16,0},
        {8,8,0},{8,8,8},
        {4,4,0},{4,12,4},{4,4,4},
        {2,2,0},{2,14,2},{2,6,2},{2,2,2},
        {1,1,0},{1,15,1},{1,7,1},{1,3,1},{1,1,1}};
#pragma unroll
    for (int s = 0; s < 15; s++) {
        const int pp = P3[s][0], dd = P3[s][1], rr = P3[s][2];
#pragma unroll
        for (int ii = 0; ii < 24; ii++) {
            if (ii + dd < 24 && (ii & pp) == rr) {
                const int jj = ii + dd;
                bool sw = ang[ii] > ang[jj];
                float ta = sw ? ang[jj] : ang[ii];
                float tb = sw ? ang[ii] : ang[jj];
                ang[ii] = ta; ang[jj] = tb;
                float xa = sw ? vx[jj] : vx[ii];
                float xb = sw ? vx[ii] : vx[jj];
                vx[ii] = xa; vx[jj] = xb;
                float ya = sw ? vy[jj] : vy[ii];
                float yb = sw ? vy[ii] : vy[jj];
                vy[ii] = ya; vy[jj] = yb;
            }
        }
    }

    // pad slots >= k with vs[0] (reference semantics), then 24-ring shoelace
    float v0x = vx[0], v0y = vy[0];
#pragma unroll
    for (int j = 1; j < 24; j++) {
        bool pd = j >= k;
        vx[j] = pd ? v0x : vx[j];
        vy[j] = pd ? v0y : vy[j];
    }
    float crs = 0.0f;
#pragma unroll
    for (int j = 0; j < 24; j++) {
        int jn = (j + 1 < 24) ? j + 1 : 0;
        crs = FADD(crs, FSUB(FMUL(vx[j], vy[jn]), FMUL(vy[j], vx[jn])));
    }
    float inter = FMUL(0.5f, fabsf(crs));

    float area1 = FMUL(pw, ph), area2 = FMUL(qw, qh);
    float uni = FSUB(FADD(area1, area2), inter);
    float iou = FDIV(inter, uni);

    out[i] = FADD(FSUB(1.0f, iou), FDIV(d2, c2d));
}

extern "C" void kernel_launch(void* const* d_in, const int* in_sizes, int n_in,
                              void* d_out, int out_size, void* d_ws, size_t ws_size,
                              hipStream_t stream) {
    const float* pred = (const float*)d_in[0];
    const float* tgt  = (const float*)d_in[1];
    float* out = (float*)d_out;
    int n = in_sizes[0] / 6;
    int block = 256;
    int grid = (n + block - 1) / block;
    riou_kernel<<<grid, block, 0, stream>>>(pred, tgt, out, n);
}

// Round 5
// 201.823 us; speedup vs baseline: 2.8015x; 2.8015x over previous
//
#include <hip/hip_runtime.h>
#include <math.h>

// Round-5: rank-and-match polygon ordering. No LDS, no dynamic indexing,
// no non-IEEE intrinsics — pure static register dataflow (round-4's
// LDS-gather/rcpf/truncated-key kernel diverged between first launch and
// graph replay; rounds 2/3 with IEEE-only register code never did).
// Ordering: full-32-bit sortable pseudo-angle keys (IEEE FDIV, exact
// monotone map of atan2f) -> stable ranks via 276 pairwise compares
// (tie -> lower slot, = jnp stable argsort) -> shoelace accumulated by
// successor-matching over pairs (reassociation-only deviation, ~2e-5 on
// the loss). Mask-deciding arithmetic (__f*_rn chains, OCML atan2f/
// cosf/sinf, sum orders) bit-identical to passing rounds 2/3.
// __launch_bounds__(256,2): VGPR budget 256 so the ~110-float live set
// (vx,vy,keys,ranks) stays in registers — round-3's spill killer.

#define FMUL __fmul_rn
#define FADD __fadd_rn
#define FSUB __fsub_rn
#define FDIV __fdiv_rn

__global__ __launch_bounds__(256, 2)
void riou_kernel(const float* __restrict__ pred,
                 const float* __restrict__ tgt,
                 float* __restrict__ out, int n)
{
    int i = blockIdx.x * blockDim.x + threadIdx.x;
    if (i >= n) return;

    const float* p = pred + 6 * (size_t)i;
    const float* q = tgt  + 6 * (size_t)i;

    const float px = p[0], py = p[1], pw = p[2], ph = p[3];
    const float qx = q[0], qy = q[1], qw = q[2], qh = q[3];

    // bit-critical transcendental sequence
    float rad1 = atan2f(p[4], p[5]);
    float cA = cosf(rad1), sA = sinf(rad1);
    float rad2 = atan2f(q[4], q[5]);
    float cB = cosf(rad2), sB = sinf(rad2);

    const float ddx[4] = {0.5f, -0.5f, -0.5f, 0.5f};
    const float ddy[4] = {0.5f, 0.5f, -0.5f, -0.5f};
    float c1x[4], c1y[4], c2x[4], c2y[4];
#pragma unroll
    for (int j = 0; j < 4; j++) {
        float cx = FMUL(ddx[j], pw), cy = FMUL(ddy[j], ph);
        c1x[j] = FADD(FSUB(FMUL(cx, cA), FMUL(cy, sA)), px);
        c1y[j] = FADD(FADD(FMUL(cx, sA), FMUL(cy, cA)), py);
        float dx2 = FMUL(ddx[j], qw), dy2 = FMUL(ddy[j], qh);
        c2x[j] = FADD(FSUB(FMUL(dx2, cB), FMUL(dy2, sB)), qx);
        c2y[j] = FADD(FADD(FMUL(dx2, sB), FMUL(dy2, cB)), qy);
    }

    // enclosing-box diagonal + center distance (frees corner liveness early)
    float minx = c1x[0], maxx = c1x[0], miny = c1y[0], maxy = c1y[0];
#pragma unroll
    for (int j = 1; j < 4; j++) {
        minx = fminf(minx, c1x[j]); maxx = fmaxf(maxx, c1x[j]);
        miny = fminf(miny, c1y[j]); maxy = fmaxf(maxy, c1y[j]);
    }
#pragma unroll
    for (int j = 0; j < 4; j++) {
        minx = fminf(minx, c2x[j]); maxx = fmaxf(maxx, c2x[j]);
        miny = fminf(miny, c2y[j]); maxy = fmaxf(maxy, c2y[j]);
    }
    float wcb = FSUB(maxx, minx), hcb = FSUB(maxy, miny);
    float c2d = FADD(FMUL(wcb, wcb), FMUL(hcb, hcb));
    float dxc = FSUB(px, qx), dyc = FSUB(py, qy);
    float d2 = FADD(FMUL(dxc, dxc), FMUL(dyc, dyc));

    // ---- phase 1: 24 candidate slots (register arrays), mask + sums ----
    float vx[24], vy[24];
    unsigned mbits = 0;
    int k = 0;
    float sx = 0.0f, sy = 0.0f;
    const float eps = 1e-6f;
    const float hieps = 1.0f + 1e-6f;

    // slots 0-3: c1 corners inside c2
    {
        float ax = c2x[0], ay = c2y[0];
        float abx = FSUB(c2x[1], ax), aby = FSUB(c2y[1], ay);
        float adx = FSUB(c2x[3], ax), ady = FSUB(c2y[3], ay);
        float dab = FADD(FMUL(abx, abx), FMUL(aby, aby));
        float dad = FADD(FMUL(adx, adx), FMUL(ady, ady));
#pragma unroll
        for (int j = 0; j < 4; j++) {
            float amx = FSUB(c1x[j], ax), amy = FSUB(c1y[j], ay);
            float pab = FDIV(FADD(FMUL(abx, amx), FMUL(aby, amy)), dab);
            float pad = FDIV(FADD(FMUL(adx, amx), FMUL(ady, amy)), dad);
            int m = (pab > -eps) & (pab < hieps) & (pad > -eps) & (pad < hieps);
            vx[j] = c1x[j]; vy[j] = c1y[j];
            mbits |= (unsigned)m << j;
            k += m;
            sx = FADD(sx, m ? c1x[j] : 0.0f);
            sy = FADD(sy, m ? c1y[j] : 0.0f);
        }
    }
    // slots 4-7: c2 corners inside c1
    {
        float ax = c1x[0], ay = c1y[0];
        float abx = FSUB(c1x[1], ax), aby = FSUB(c1y[1], ay);
        float adx = FSUB(c1x[3], ax), ady = FSUB(c1y[3], ay);
        float dab = FADD(FMUL(abx, abx), FMUL(aby, aby));
        float dad = FADD(FMUL(adx, adx), FMUL(ady, ady));
#pragma unroll
        for (int j = 0; j < 4; j++) {
            float amx = FSUB(c2x[j], ax), amy = FSUB(c2y[j], ay);
            float pab = FDIV(FADD(FMUL(abx, amx), FMUL(aby, amy)), dab);
            float pad = FDIV(FADD(FMUL(adx, amx), FMUL(ady, amy)), dad);
            int m = (pab > -eps) & (pab < hieps) & (pad > -eps) & (pad < hieps);
            vx[4 + j] = c2x[j]; vy[4 + j] = c2y[j];
            mbits |= (unsigned)m << (4 + j);
            k += m;
            sx = FADD(sx, m ? c2x[j] : 0.0f);
            sy = FADD(sy, m ? c2y[j] : 0.0f);
        }
    }
    // slots 8-23: edge intersections, slot = 8 + 4*e1 + e2
#pragma unroll
    for (int e1 = 0; e1 < 4; e1++) {
        float x1 = c1x[e1], y1 = c1y[e1];
        float x2 = c1x[(e1 + 1) & 3], y2 = c1y[(e1 + 1) & 3];
        float ex = FSUB(x2, x1), ey = FSUB(y2, y1);
#pragma unroll
        for (int e2 = 0; e2 < 4; e2++) {
            float x3 = c2x[e2], y3 = c2y[e2];
            float x4 = c2x[(e2 + 1) & 3], y4 = c2y[(e2 + 1) & 3];
            float num_t = FSUB(FMUL(ex, FSUB(y3, y1)), FMUL(ey, FSUB(x3, x1)));
            float den_t = FSUB(FMUL(ex, FSUB(y3, y4)), FMUL(ey, FSUB(x3, x4)));
            float tq = FDIV(num_t, den_t);   // den==0 -> inf/nan -> masked out
            float fx = FSUB(x4, x3), fy = FSUB(y4, y3);
            float num_u = FSUB(FMUL(fx, FSUB(y1, y3)), FMUL(fy, FSUB(x1, x3)));
            float den_u = FSUB(FMUL(fx, FSUB(y1, y2)), FMUL(fy, FSUB(x1, x2)));
            float uq = FDIV(num_u, den_u);
            int m = (tq > 0.0f) & (tq < 1.0f) & (uq > 0.0f) & (uq < 1.0f);
            float ix = FADD(x1, FMUL(tq, ex));   // garbage if masked; gated below
            float iy = FADD(y1, FMUL(tq, ey));
            int s = 8 + 4 * e1 + e2;
            vx[s] = ix; vy[s] = iy;
            mbits |= (unsigned)m << s;
            k += m;
            sx = FADD(sx, m ? ix : 0.0f);
            sy = FADD(sy, m ? iy : 0.0f);
        }
    }

    // centroid
    float kk = (float)(k > 0 ? k : 1);
    float mx = FDIV(sx, kk), my = FDIV(sy, kk);

    // ---- phase 2: recenter (masked -> 0) + full 32-bit sortable keys ----
    unsigned keys[24];
#pragma unroll
    for (int j = 0; j < 24; j++) {
        int m = (mbits >> j) & 1u;
        float wx2 = m ? FSUB(vx[j], mx) : 0.0f;
        float wy2 = m ? FSUB(vy[j], my) : 0.0f;
        vx[j] = wx2; vy[j] = wy2;                 // garbage cleared if masked
        float dsum = FADD(fabsf(wx2), fabsf(wy2));
        float rs = (dsum > 0.0f) ? FDIV(wx2, dsum) : 1.0f;  // IEEE div
        float key = copysignf(FSUB(1.0f, rs), wy2);  // monotone map of atan2
        unsigned sb = __float_as_uint(key);
        unsigned u = sb ^ (unsigned)(((int)sb >> 31) | (int)0x80000000);
        keys[j] = m ? u : 0xFFFFFFFFu;            // masked sort last (u<0xC1e6... always)
    }

    // ---- phase 3: stable ranks via pairwise compares (l<j: tie -> l first) ----
    int ranks[24];
#pragma unroll
    for (int j = 0; j < 24; j++) ranks[j] = 0;
#pragma unroll
    for (int l = 0; l < 24; l++) {
#pragma unroll
        for (int j = l + 1; j < 24; j++) {
            bool le = keys[l] <= keys[j];
            ranks[j] += le ? 1 : 0;
            ranks[l] += le ? 0 : 1;
        }
    }

    // successor rank per slot: rank+1 (wrap k->0); masked -> 255 (matches none)
    int rjn[24];
#pragma unroll
    for (int j = 0; j < 24; j++) {
        int rn = ranks[j] + 1;
        rn = (rn == k) ? 0 : rn;
        rjn[j] = ((mbits >> j) & 1u) ? rn : 255;
    }

    // ---- phase 4: shoelace by successor matching over unordered pairs ----
    // succ(l)==j contributes +cross(v_l,v_j); succ(j)==l contributes
    // cross(v_j,v_l) = -cross(v_l,v_j). Both true (k==2) cancels exactly.
    float crs = 0.0f;
#pragma unroll
    for (int l = 0; l < 24; l++) {
#pragma unroll
        for (int j = l + 1; j < 24; j++) {
            float cr = FSUB(FMUL(vx[l], vy[j]), FMUL(vy[l], vx[j]));
            float tpos = (ranks[j] == rjn[l]) ? cr : 0.0f;
            float tneg = (ranks[l] == rjn[j]) ? cr : 0.0f;
            crs = FADD(crs, FSUB(tpos, tneg));
        }
    }
    float inter = FMUL(0.5f, fabsf(crs));

    float area1 = FMUL(pw, ph), area2 = FMUL(qw, qh);
    float uni = FSUB(FADD(area1, area2), inter);
    float iou = FDIV(inter, uni);

    out[i] = FADD(FSUB(1.0f, iou), FDIV(d2, c2d));
}

extern "C" void kernel_launch(void* const* d_in, const int* in_sizes, int n_in,
                              void* d_out, int out_size, void* d_ws, size_t ws_size,
                              hipStream_t stream) {
    const float* pred = (const float*)d_in[0];
    const float* tgt  = (const float*)d_in[1];
    float* out = (float*)d_out;
    int n = in_sizes[0] / 6;
    int block = 256;
    int grid = (n + block - 1) / block;
    riou_kernel<<<grid, block, 0, stream>>>(pred, tgt, out, n);
}

// Round 6
// 143.998 us; speedup vs baseline: 3.9265x; 1.4016x over previous
//
#include <hip/hip_runtime.h>
#include <math.h>

// Round-6: streaming extract-min ordering + rcp mask-ratios.
// Round-5 measured ~11k VALU insts/thread; the O(n^2)=276-pair rank +
// successor-match machinery was >40%. Replaced by 8 unrolled extract-min
// passes over unique u64 keys (full 32-bit pseudo-angle key || 5-bit slot
// -> stable tie-break == jnp stable argsort, no truncation), shoelace
// streamed through extraction (empty pass adds exact +0: bx,by init to
// prev => cross(prev,prev)==0), rare k>8 tail loop for noise-mask cases.
// Mask-deciding ratios t,u,p_ab,p_ad via v_rcp_f32+mul: 1-ulp flips occur
// only at area-continuous boundaries; rcpf(0)=inf reproduces den==0->mask
// semantics. Corner/trig chains and all sum orders bit-identical to the
// passing round-5 kernel. Register-only dataflow (no LDS — round-4 lesson).

#define FMUL __fmul_rn
#define FADD __fadd_rn
#define FSUB __fsub_rn
#define FDIV __fdiv_rn

typedef unsigned long long u64;

__device__ __forceinline__ float rdiv(float num, float den) {
    return FMUL(num, __builtin_amdgcn_rcpf(den));
}

__global__ __launch_bounds__(256, 2)
void riou_kernel(const float* __restrict__ pred,
                 const float* __restrict__ tgt,
                 float* __restrict__ out, int n)
{
    int i = blockIdx.x * blockDim.x + threadIdx.x;
    if (i >= n) return;

    const float* p = pred + 6 * (size_t)i;
    const float* q = tgt  + 6 * (size_t)i;

    const float px = p[0], py = p[1], pw = p[2], ph = p[3];
    const float qx = q[0], qy = q[1], qw = q[2], qh = q[3];

    // bit-critical transcendental sequence
    float rad1 = atan2f(p[4], p[5]);
    float cA = cosf(rad1), sA = sinf(rad1);
    float rad2 = atan2f(q[4], q[5]);
    float cB = cosf(rad2), sB = sinf(rad2);

    const float ddx[4] = {0.5f, -0.5f, -0.5f, 0.5f};
    const float ddy[4] = {0.5f, 0.5f, -0.5f, -0.5f};
    float c1x[4], c1y[4], c2x[4], c2y[4];
#pragma unroll
    for (int j = 0; j < 4; j++) {
        float cx = FMUL(ddx[j], pw), cy = FMUL(ddy[j], ph);
        c1x[j] = FADD(FSUB(FMUL(cx, cA), FMUL(cy, sA)), px);
        c1y[j] = FADD(FADD(FMUL(cx, sA), FMUL(cy, cA)), py);
        float dx2 = FMUL(ddx[j], qw), dy2 = FMUL(ddy[j], qh);
        c2x[j] = FADD(FSUB(FMUL(dx2, cB), FMUL(dy2, sB)), qx);
        c2y[j] = FADD(FADD(FMUL(dx2, sB), FMUL(dy2, cB)), qy);
    }

    // enclosing-box diagonal + center distance
    float minx = c1x[0], maxx = c1x[0], miny = c1y[0], maxy = c1y[0];
#pragma unroll
    for (int j = 1; j < 4; j++) {
        minx = fminf(minx, c1x[j]); maxx = fmaxf(maxx, c1x[j]);
        miny = fminf(miny, c1y[j]); maxy = fmaxf(maxy, c1y[j]);
    }
#pragma unroll
    for (int j = 0; j < 4; j++) {
        minx = fminf(minx, c2x[j]); maxx = fmaxf(maxx, c2x[j]);
        miny = fminf(miny, c2y[j]); maxy = fmaxf(maxy, c2y[j]);
    }
    float wcb = FSUB(maxx, minx), hcb = FSUB(maxy, miny);
    float c2d = FADD(FMUL(wcb, wcb), FMUL(hcb, hcb));
    float dxc = FSUB(px, qx), dyc = FSUB(py, qy);
    float d2 = FADD(FMUL(dxc, dxc), FMUL(dyc, dyc));

    // ---- phase 1: 24 candidate slots (register arrays), mask + sums ----
    float vx[24], vy[24];
    unsigned mbits = 0;
    int k = 0;
    float sx = 0.0f, sy = 0.0f;
    const float eps = 1e-6f;
    const float hieps = 1.0f + 1e-6f;

    // slots 0-3: c1 corners inside c2
    {
        float ax = c2x[0], ay = c2y[0];
        float abx = FSUB(c2x[1], ax), aby = FSUB(c2y[1], ay);
        float adx = FSUB(c2x[3], ax), ady = FSUB(c2y[3], ay);
        float dab = FADD(FMUL(abx, abx), FMUL(aby, aby));
        float dad = FADD(FMUL(adx, adx), FMUL(ady, ady));
        float rab = __builtin_amdgcn_rcpf(dab);
        float rad = __builtin_amdgcn_rcpf(dad);
#pragma unroll
        for (int j = 0; j < 4; j++) {
            float amx = FSUB(c1x[j], ax), amy = FSUB(c1y[j], ay);
            float pab = FMUL(FADD(FMUL(abx, amx), FMUL(aby, amy)), rab);
            float pad = FMUL(FADD(FMUL(adx, amx), FMUL(ady, amy)), rad);
            int m = (pab > -eps) & (pab < hieps) & (pad > -eps) & (pad < hieps);
            vx[j] = c1x[j]; vy[j] = c1y[j];
            mbits |= (unsigned)m << j;
            k += m;
            sx = FADD(sx, m ? c1x[j] : 0.0f);
            sy = FADD(sy, m ? c1y[j] : 0.0f);
        }
    }
    // slots 4-7: c2 corners inside c1
    {
        float ax = c1x[0], ay = c1y[0];
        float abx = FSUB(c1x[1], ax), aby = FSUB(c1y[1], ay);
        float adx = FSUB(c1x[3], ax), ady = FSUB(c1y[3], ay);
        float dab = FADD(FMUL(abx, abx), FMUL(aby, aby));
        float dad = FADD(FMUL(adx, adx), FMUL(ady, ady));
        float rab = __builtin_amdgcn_rcpf(dab);
        float rad = __builtin_amdgcn_rcpf(dad);
#pragma unroll
        for (int j = 0; j < 4; j++) {
            float amx = FSUB(c2x[j], ax), amy = FSUB(c2y[j], ay);
            float pab = FMUL(FADD(FMUL(abx, amx), FMUL(aby, amy)), rab);
            float pad = FMUL(FADD(FMUL(adx, amx), FMUL(ady, amy)), rad);
            int m = (pab > -eps) & (pab < hieps) & (pad > -eps) & (pad < hieps);
            vx[4 + j] = c2x[j]; vy[4 + j] = c2y[j];
            mbits |= (unsigned)m << (4 + j);
            k += m;
            sx = FADD(sx, m ? c2x[j] : 0.0f);
            sy = FADD(sy, m ? c2y[j] : 0.0f);
        }
    }
    // slots 8-23: edge intersections, slot = 8 + 4*e1 + e2
#pragma unroll
    for (int e1 = 0; e1 < 4; e1++) {
        float x1 = c1x[e1], y1 = c1y[e1];
        float x2 = c1x[(e1 + 1) & 3], y2 = c1y[(e1 + 1) & 3];
        float ex = FSUB(x2, x1), ey = FSUB(y2, y1);
#pragma unroll
        for (int e2 = 0; e2 < 4; e2++) {
            float x3 = c2x[e2], y3 = c2y[e2];
            float x4 = c2x[(e2 + 1) & 3], y4 = c2y[(e2 + 1) & 3];
            float num_t = FSUB(FMUL(ex, FSUB(y3, y1)), FMUL(ey, FSUB(x3, x1)));
            float den_t = FSUB(FMUL(ex, FSUB(y3, y4)), FMUL(ey, FSUB(x3, x4)));
            float tq = rdiv(num_t, den_t);   // den==0 -> inf/nan -> masked
            float fx = FSUB(x4, x3), fy = FSUB(y4, y3);
            float num_u = FSUB(FMUL(fx, FSUB(y1, y3)), FMUL(fy, FSUB(x1, x3)));
            float den_u = FSUB(FMUL(fx, FSUB(y1, y2)), FMUL(fy, FSUB(x1, x2)));
            float uq = rdiv(num_u, den_u);
            int m = (tq > 0.0f) & (tq < 1.0f) & (uq > 0.0f) & (uq < 1.0f);
            float ix = FADD(x1, FMUL(tq, ex));   // garbage if masked; gated
            float iy = FADD(y1, FMUL(tq, ey));
            int s = 8 + 4 * e1 + e2;
            vx[s] = ix; vy[s] = iy;
            mbits |= (unsigned)m << s;
            k += m;
            sx = FADD(sx, m ? ix : 0.0f);
            sy = FADD(sy, m ? iy : 0.0f);
        }
    }

    // centroid (IEEE div: shifts all keys coherently, keep exact)
    float kk = (float)(k > 0 ? k : 1);
    float mx = FDIV(sx, kk), my = FDIV(sy, kk);

    // ---- phase 2: recenter (masked -> 0) + unique u64 sort keys ----
    // key32: sortable-uint of pseudo-angle (monotone in atan2); u64 appends
    // slot -> all keys distinct, ties resolve to lower slot (stable argsort).
    u64 ukey[24];
#pragma unroll
    for (int j = 0; j < 24; j++) {
        int m = (mbits >> j) & 1u;
        float wx2 = m ? FSUB(vx[j], mx) : 0.0f;
        float wy2 = m ? FSUB(vy[j], my) : 0.0f;
        vx[j] = wx2; vy[j] = wy2;
        float dsum = FADD(fabsf(wx2), fabsf(wy2));
        float rs = (dsum > 0.0f) ? FMUL(wx2, __builtin_amdgcn_rcpf(dsum)) : 1.0f;
        float keyf = copysignf(FSUB(1.0f, rs), wy2);
        unsigned sb = __float_as_uint(keyf);
        unsigned u = sb ^ (unsigned)(((int)sb >> 31) | (int)0x80000000);
        u = m ? u : 0xFFFFFFFFu;                  // masked -> never extracted
        ukey[j] = ((u64)u << 5) | (unsigned)j;
    }

    // ---- phase 3: streaming extract-min + shoelace ----
    // Pass s finds min ukey in (prevkey, MASKED_MIN); masked slots have
    // ukey >= MASKED_MIN and are never selected. Empty pass: bx,by stay
    // prev -> cross(prev,prev) == exact 0 -> sum bit-equal to the
    // reference's padded 24-ring (pads add +0, closing term last).
    const u64 MASKED_MIN = ((u64)0xFFFFFFFFu) << 5;
    u64 prevkey = 0;
    float firstx, firsty, prevx, prevy;
    float crs = 0.0f;
    {   // pass 0: global min (prevkey=0 < every key)
        u64 best = MASKED_MIN; float bx = 0.0f, by = 0.0f;
#pragma unroll
        for (int j = 0; j < 24; j++) {
            bool c = (ukey[j] > prevkey) & (ukey[j] < best);
            best = c ? ukey[j] : best;
            bx = c ? vx[j] : bx;
            by = c ? vy[j] : by;
        }
        firstx = bx; firsty = by; prevx = bx; prevy = by; prevkey = best;
    }
#pragma unroll
    for (int s = 1; s < 8; s++) {
        u64 best = MASKED_MIN; float bx = prevx, by = prevy;
#pragma unroll
        for (int j = 0; j < 24; j++) {
            bool c = (ukey[j] > prevkey) & (ukey[j] < best);
            best = c ? ukey[j] : best;
            bx = c ? vx[j] : bx;
            by = c ? vy[j] : by;
        }
        crs = FADD(crs, FSUB(FMUL(prevx, by), FMUL(prevy, bx)));
        prevx = bx; prevy = by; prevkey = best;
    }
    // rare tail: noise masks can push k past the geometric bound of 8
    for (int s = 8; s < k; s++) {
        u64 best = MASKED_MIN; float bx = prevx, by = prevy;
#pragma unroll
        for (int j = 0; j < 24; j++) {
            bool c = (ukey[j] > prevkey) & (ukey[j] < best);
            best = c ? ukey[j] : best;
            bx = c ? vx[j] : bx;
            by = c ? vy[j] : by;
        }
        crs = FADD(crs, FSUB(FMUL(prevx, by), FMUL(prevy, bx)));
        prevx = bx; prevy = by; prevkey = best;
    }
    // close the ring
    crs = FADD(crs, FSUB(FMUL(prevx, firsty), FMUL(prevy, firstx)));
    float inter = FMUL(0.5f, fabsf(crs));

    float area1 = FMUL(pw, ph), area2 = FMUL(qw, qh);
    float uni = FSUB(FADD(area1, area2), inter);
    float iou = FDIV(inter, uni);

    out[i] = FADD(FSUB(1.0f, iou), FDIV(d2, c2d));
}

extern "C" void kernel_launch(void* const* d_in, const int* in_sizes, int n_in,
                              void* d_out, int out_size, void* d_ws, size_t ws_size,
                              hipStream_t stream) {
    const float* pred = (const float*)d_in[0];
    const float* tgt  = (const float*)d_in[1];
    float* out = (float*)d_out;
    int n = in_sizes[0] / 6;
    int block = 256;
    int grid = (n + block - 1) / block;
    riou_kernel<<<grid, block, 0, stream>>>(pred, tgt, out, n);
}

// Round 8
// 131.272 us; speedup vs baseline: 4.3071x; 1.0969x over previous
//
#include <hip/hip_runtime.h>
#include <math.h>

// Round-8 = round-6 (passing, 80us) + the two SAFE round-7 cuts:
//  - u32 packed extract-min keys (27-bit pseudo-angle | 5-bit slot; round-4
//    first-check measured this truncation at absmax 0.0078).
//  - den_u == -den_t bitwise (IEEE negation commutes with rounding;
//    rcp(-x) = -rcp(x)), so u in (0,1) <=> num_u*rcp(den_t) in (-1,0).
// REVERTED: trig-identity corners. Round-7 lesson: near-collinear masks are
// decided by catastrophically-cancelled num_t — pure rounding noise of the
// corner BITS. The expected output embeds that noise, so the corner chain
// (atan2f/cosf/sinf + __f*_rn rotation) must stay bit-frozen (absmax 0.43
// when perturbed by 1 ulp). Register-only dataflow (round-4 lesson: no LDS).

#define FMUL __fmul_rn
#define FADD __fadd_rn
#define FSUB __fsub_rn
#define FDIV __fdiv_rn

__device__ __forceinline__ float rcpf_(float x) { return __builtin_amdgcn_rcpf(x); }

__global__ __launch_bounds__(256, 2)
void riou_kernel(const float* __restrict__ pred,
                 const float* __restrict__ tgt,
                 float* __restrict__ out, int n)
{
    int i = blockIdx.x * blockDim.x + threadIdx.x;
    if (i >= n) return;

    const float* p = pred + 6 * (size_t)i;
    const float* q = tgt  + 6 * (size_t)i;

    const float px = p[0], py = p[1], pw = p[2], ph = p[3];
    const float qx = q[0], qy = q[1], qw = q[2], qh = q[3];

    // bit-critical transcendental sequence — DO NOT substitute identities
    float rad1 = atan2f(p[4], p[5]);
    float cA = cosf(rad1), sA = sinf(rad1);
    float rad2 = atan2f(q[4], q[5]);
    float cB = cosf(rad2), sB = sinf(rad2);

    const float ddx[4] = {0.5f, -0.5f, -0.5f, 0.5f};
    const float ddy[4] = {0.5f, 0.5f, -0.5f, -0.5f};
    float c1x[4], c1y[4], c2x[4], c2y[4];
#pragma unroll
    for (int j = 0; j < 4; j++) {
        float cx = FMUL(ddx[j], pw), cy = FMUL(ddy[j], ph);
        c1x[j] = FADD(FSUB(FMUL(cx, cA), FMUL(cy, sA)), px);
        c1y[j] = FADD(FADD(FMUL(cx, sA), FMUL(cy, cA)), py);
        float dx2 = FMUL(ddx[j], qw), dy2 = FMUL(ddy[j], qh);
        c2x[j] = FADD(FSUB(FMUL(dx2, cB), FMUL(dy2, sB)), qx);
        c2y[j] = FADD(FADD(FMUL(dx2, sB), FMUL(dy2, cB)), qy);
    }

    // enclosing-box diagonal + center distance
    float minx = c1x[0], maxx = c1x[0], miny = c1y[0], maxy = c1y[0];
#pragma unroll
    for (int j = 1; j < 4; j++) {
        minx = fminf(minx, c1x[j]); maxx = fmaxf(maxx, c1x[j]);
        miny = fminf(miny, c1y[j]); maxy = fmaxf(maxy, c1y[j]);
    }
#pragma unroll
    for (int j = 0; j < 4; j++) {
        minx = fminf(minx, c2x[j]); maxx = fmaxf(maxx, c2x[j]);
        miny = fminf(miny, c2y[j]); maxy = fmaxf(maxy, c2y[j]);
    }
    float wcb = FSUB(maxx, minx), hcb = FSUB(maxy, miny);
    float c2d = FADD(FMUL(wcb, wcb), FMUL(hcb, hcb));
    float dxc = FSUB(px, qx), dyc = FSUB(py, qy);
    float d2 = FADD(FMUL(dxc, dxc), FMUL(dyc, dyc));

    // ---- phase 1: 24 candidate slots, mask bits + masked sums ----
    float vx[24], vy[24];
    unsigned mbits = 0;
    int k = 0;
    float sx = 0.0f, sy = 0.0f;
    const float eps = 1e-6f;
    const float hieps = 1.0f + 1e-6f;

    // slots 0-3: c1 corners inside c2
    {
        float ax = c2x[0], ay = c2y[0];
        float abx = FSUB(c2x[1], ax), aby = FSUB(c2y[1], ay);
        float adx = FSUB(c2x[3], ax), ady = FSUB(c2y[3], ay);
        float rab = rcpf_(FADD(FMUL(abx, abx), FMUL(aby, aby)));
        float rad = rcpf_(FADD(FMUL(adx, adx), FMUL(ady, ady)));
#pragma unroll
        for (int j = 0; j < 4; j++) {
            float amx = FSUB(c1x[j], ax), amy = FSUB(c1y[j], ay);
            float pab = FMUL(FADD(FMUL(abx, amx), FMUL(aby, amy)), rab);
            float pad = FMUL(FADD(FMUL(adx, amx), FMUL(ady, amy)), rad);
            int m = (pab > -eps) & (pab < hieps) & (pad > -eps) & (pad < hieps);
            vx[j] = c1x[j]; vy[j] = c1y[j];
            mbits |= (unsigned)m << j;
            k += m;
            sx = FADD(sx, m ? c1x[j] : 0.0f);
            sy = FADD(sy, m ? c1y[j] : 0.0f);
        }
    }
    // slots 4-7: c2 corners inside c1
    {
        float ax = c1x[0], ay = c1y[0];
        float abx = FSUB(c1x[1], ax), aby = FSUB(c1y[1], ay);
        float adx = FSUB(c1x[3], ax), ady = FSUB(c1y[3], ay);
        float rab = rcpf_(FADD(FMUL(abx, abx), FMUL(aby, aby)));
        float rad = rcpf_(FADD(FMUL(adx, adx), FMUL(ady, ady)));
#pragma unroll
        for (int j = 0; j < 4; j++) {
            float amx = FSUB(c2x[j], ax), amy = FSUB(c2y[j], ay);
            float pab = FMUL(FADD(FMUL(abx, amx), FMUL(aby, amy)), rab);
            float pad = FMUL(FADD(FMUL(adx, amx), FMUL(ady, amy)), rad);
            int m = (pab > -eps) & (pab < hieps) & (pad > -eps) & (pad < hieps);
            vx[4 + j] = c2x[j]; vy[4 + j] = c2y[j];
            mbits |= (unsigned)m << (4 + j);
            k += m;
            sx = FADD(sx, m ? c2x[j] : 0.0f);
            sy = FADD(sy, m ? c2y[j] : 0.0f);
        }
    }
    // slots 8-23: edge intersections, slot = 8 + 4*e1 + e2.
    // den_u = -den_t exactly -> one rcp per pair; u in (0,1) <=> uq in (-1,0).
    float fex[4], fey[4];
#pragma unroll
    for (int e2 = 0; e2 < 4; e2++) {
        fex[e2] = FSUB(c2x[(e2 + 1) & 3], c2x[e2]);
        fey[e2] = FSUB(c2y[(e2 + 1) & 3], c2y[e2]);
    }
#pragma unroll
    for (int e1 = 0; e1 < 4; e1++) {
        float x1 = c1x[e1], y1 = c1y[e1];
        float ex = FSUB(c1x[(e1 + 1) & 3], x1), ey = FSUB(c1y[(e1 + 1) & 3], y1);
#pragma unroll
        for (int e2 = 0; e2 < 4; e2++) {
            float dx31 = FSUB(c2x[e2], x1), dy31 = FSUB(c2y[e2], y1);
            float num_t = FSUB(FMUL(ex, dy31), FMUL(ey, dx31));
            float den_t = FSUB(FMUL(ey, fex[e2]), FMUL(ex, fey[e2]));
            float rd = rcpf_(den_t);          // den==0 -> inf -> masked below
            float tq = FMUL(num_t, rd);
            float num_u = FSUB(FMUL(fey[e2], dx31), FMUL(fex[e2], dy31));
            float uq = FMUL(num_u, rd);       // == -u exactly
            int m = (tq > 0.0f) & (tq < 1.0f) & (uq < 0.0f) & (uq > -1.0f);
            float ix = FADD(x1, FMUL(tq, ex));   // garbage if masked; gated
            float iy = FADD(y1, FMUL(tq, ey));
            int s = 8 + 4 * e1 + e2;
            vx[s] = ix; vy[s] = iy;
            mbits |= (unsigned)m << s;
            k += m;
            sx = FADD(sx, m ? ix : 0.0f);
            sy = FADD(sy, m ? iy : 0.0f);
        }
    }

    // centroid (IEEE div: feeds every recentered coordinate)
    float kk = (float)(k > 0 ? k : 1);
    float mx = FDIV(sx, kk), my = FDIV(sy, kk);

    // ---- phase 2: recenter + u32 packed keys (27-bit angle | 5-bit slot) ----
    unsigned pk[24];
#pragma unroll
    for (int j = 0; j < 24; j++) {
        int m = (mbits >> j) & 1u;
        float wx2 = m ? FSUB(vx[j], mx) : 0.0f;
        float wy2 = m ? FSUB(vy[j], my) : 0.0f;
        vx[j] = wx2; vy[j] = wy2;
        float dsum = FADD(fabsf(wx2), fabsf(wy2));
        float rs = (dsum > 0.0f) ? FMUL(wx2, rcpf_(dsum)) : 1.0f;
        float keyf = copysignf(FSUB(1.0f, rs), wy2);   // monotone in atan2
        unsigned sb = __float_as_uint(keyf);
        unsigned u = sb ^ (unsigned)(((int)sb >> 31) | (int)0x80000000);
        pk[j] = m ? ((u & 0xFFFFFFE0u) | (unsigned)j)
                  : (0xFFFFFFE0u | (unsigned)j);       // masked: sorts last
    }

    // ---- phase 3: streaming extract-min + shoelace ----
    // keyf in [-2,2] -> sortable in [~0x3F.., 0xC1..] < MASKED_MIN, > 0.
    const unsigned MASKED_MIN = 0xFFFFFFE0u;
    unsigned prevkey = 0;
    float firstx, firsty, prevx, prevy;
    float crs = 0.0f;
    {   // pass 0: global min
        unsigned best = MASKED_MIN; float bx = 0.0f, by = 0.0f;
#pragma unroll
        for (int j = 0; j < 24; j++) {
            bool c = (pk[j] > prevkey) & (pk[j] < best);
            best = c ? pk[j] : best;
            bx = c ? vx[j] : bx;
            by = c ? vy[j] : by;
        }
        firstx = bx; firsty = by; prevx = bx; prevy = by; prevkey = best;
    }
#pragma unroll
    for (int s = 1; s < 8; s++) {
        unsigned best = MASKED_MIN; float bx = prevx, by = prevy;
#pragma unroll
        for (int j = 0; j < 24; j++) {
            bool c = (pk[j] > prevkey) & (pk[j] < best);
            best = c ? pk[j] : best;
            bx = c ? vx[j] : bx;
            by = c ? vy[j] : by;
        }
        // empty pass: bx,by == prev -> cross == exact 0
        crs = FADD(crs, FSUB(FMUL(prevx, by), FMUL(prevy, bx)));
        prevx = bx; prevy = by; prevkey = best;
    }
    // rare tail: noise masks can push k past the geometric bound of 8
    for (int s = 8; s < k; s++) {
        unsigned best = MASKED_MIN; float bx = prevx, by = prevy;
#pragma unroll
        for (int j = 0; j < 24; j++) {
            bool c = (pk[j] > prevkey) & (pk[j] < best);
            best = c ? pk[j] : best;
            bx = c ? vx[j] : bx;
            by = c ? vy[j] : by;
        }
        crs = FADD(crs, FSUB(FMUL(prevx, by), FMUL(prevy, bx)));
        prevx = bx; prevy = by; prevkey = best;
    }
    // close the ring
    crs = FADD(crs, FSUB(FMUL(prevx, firsty), FMUL(prevy, firstx)));
    float inter = FMUL(0.5f, fabsf(crs));

    float area1 = FMUL(pw, ph), area2 = FMUL(qw, qh);
    float uni = FSUB(FADD(area1, area2), inter);
    float iou = FMUL(inter, rcpf_(uni));

    out[i] = FADD(FSUB(1.0f, iou), FMUL(d2, rcpf_(c2d)));
}

extern "C" void kernel_launch(void* const* d_in, const int* in_sizes, int n_in,
                              void* d_out, int out_size, void* d_ws, size_t ws_size,
                              hipStream_t stream) {
    const float* pred = (const float*)d_in[0];
    const float* tgt  = (const float*)d_in[1];
    float* out = (float*)d_out;
    int n = in_sizes[0] / 6;
    int block = 256;
    int grid = (n + block - 1) / block;
    riou_kernel<<<grid, block, 0, stream>>>(pred, tgt, out, n);
}

// Round 9
// 127.345 us; speedup vs baseline: 4.4399x; 1.0308x over previous
//
#include <hip/hip_runtime.h>
#include <math.h>

// Round-9 = round-8 numerics (bit-identical arithmetic) + ILP restructure.
//  - Extract-min via rotation trick: w[j] = pk[j] - (prevkey+1) mod 2^32.
//    All keys (real in [0x3F..,0xC2..], masked 0xFFFFFFE0|j) span < 2^31,
//    so rotation preserves circular order: un-extracted real keys < masked
//    < wrapped-extracted. Condition = single u32 compare.
//  - 4 independent chains of 6 + 3 combines per pass: dependency depth ~16
//    vs round-8's ~100 serial cndmasks (the measured 14% VALU idle at 2.9
//    waves/SIMD).
//  - Pass gated by s<k (act=false selects prev payload -> cross(prev,prev)
//    == exact IEEE 0 == round-8 empty-pass semantics).
//  - k = popc(mbits); masked-slot key-gen un-gated (garbage payload provably
//    never selected). float2 input loads.
// FROZEN (bit-critical, round-7 lesson): atan2f/cosf/sinf + __f*_rn corner
// chain, mask ratios, masked sx/sy left-fold sum order, centroid FDIV.
// Register-only dataflow (round-4 lesson: no LDS).

#define FMUL __fmul_rn
#define FADD __fadd_rn
#define FSUB __fsub_rn
#define FDIV __fdiv_rn

__device__ __forceinline__ float rcpf_(float x) { return __builtin_amdgcn_rcpf(x); }

__global__ __launch_bounds__(256, 2)
void riou_kernel(const float* __restrict__ pred,
                 const float* __restrict__ tgt,
                 float* __restrict__ out, int n)
{
    int i = blockIdx.x * blockDim.x + threadIdx.x;
    if (i >= n) return;

    const float2* p2 = (const float2*)(pred + 6 * (size_t)i);
    const float2* q2 = (const float2*)(tgt  + 6 * (size_t)i);
    float2 pa = p2[0], pb = p2[1], pc2 = p2[2];
    float2 qa = q2[0], qb = q2[1], qc2 = q2[2];
    const float px = pa.x, py = pa.y, pw = pb.x, ph = pb.y;
    const float qx = qa.x, qy = qa.y, qw = qb.x, qh = qb.y;

    // bit-critical transcendental sequence — DO NOT substitute identities
    float rad1 = atan2f(pc2.x, pc2.y);
    float cA = cosf(rad1), sA = sinf(rad1);
    float rad2 = atan2f(qc2.x, qc2.y);
    float cB = cosf(rad2), sB = sinf(rad2);

    const float ddx[4] = {0.5f, -0.5f, -0.5f, 0.5f};
    const float ddy[4] = {0.5f, 0.5f, -0.5f, -0.5f};
    float c1x[4], c1y[4], c2x[4], c2y[4];
#pragma unroll
    for (int j = 0; j < 4; j++) {
        float cx = FMUL(ddx[j], pw), cy = FMUL(ddy[j], ph);
        c1x[j] = FADD(FSUB(FMUL(cx, cA), FMUL(cy, sA)), px);
        c1y[j] = FADD(FADD(FMUL(cx, sA), FMUL(cy, cA)), py);
        float dx2 = FMUL(ddx[j], qw), dy2 = FMUL(ddy[j], qh);
        c2x[j] = FADD(FSUB(FMUL(dx2, cB), FMUL(dy2, sB)), qx);
        c2y[j] = FADD(FADD(FMUL(dx2, sB), FMUL(dy2, cB)), qy);
    }

    // enclosing-box diagonal + center distance
    float minx = c1x[0], maxx = c1x[0], miny = c1y[0], maxy = c1y[0];
#pragma unroll
    for (int j = 1; j < 4; j++) {
        minx = fminf(minx, c1x[j]); maxx = fmaxf(maxx, c1x[j]);
        miny = fminf(miny, c1y[j]); maxy = fmaxf(maxy, c1y[j]);
    }
#pragma unroll
    for (int j = 0; j < 4; j++) {
        minx = fminf(minx, c2x[j]); maxx = fmaxf(maxx, c2x[j]);
        miny = fminf(miny, c2y[j]); maxy = fmaxf(maxy, c2y[j]);
    }
    float wcb = FSUB(maxx, minx), hcb = FSUB(maxy, miny);
    float c2d = FADD(FMUL(wcb, wcb), FMUL(hcb, hcb));
    float dxc = FSUB(px, qx), dyc = FSUB(py, qy);
    float d2 = FADD(FMUL(dxc, dxc), FMUL(dyc, dyc));

    // ---- phase 1: 24 candidate slots, mask bits + masked sums ----
    float vx[24], vy[24];
    unsigned mbits = 0;
    float sx = 0.0f, sy = 0.0f;
    const float eps = 1e-6f;
    const float hieps = 1.0f + 1e-6f;

    // slots 0-3: c1 corners inside c2
    {
        float ax = c2x[0], ay = c2y[0];
        float abx = FSUB(c2x[1], ax), aby = FSUB(c2y[1], ay);
        float adx = FSUB(c2x[3], ax), ady = FSUB(c2y[3], ay);
        float rab = rcpf_(FADD(FMUL(abx, abx), FMUL(aby, aby)));
        float rad = rcpf_(FADD(FMUL(adx, adx), FMUL(ady, ady)));
#pragma unroll
        for (int j = 0; j < 4; j++) {
            float amx = FSUB(c1x[j], ax), amy = FSUB(c1y[j], ay);
            float pab = FMUL(FADD(FMUL(abx, amx), FMUL(aby, amy)), rab);
            float pad = FMUL(FADD(FMUL(adx, amx), FMUL(ady, amy)), rad);
            int m = (pab > -eps) & (pab < hieps) & (pad > -eps) & (pad < hieps);
            vx[j] = c1x[j]; vy[j] = c1y[j];
            mbits |= (unsigned)m << j;
            sx = FADD(sx, m ? c1x[j] : 0.0f);
            sy = FADD(sy, m ? c1y[j] : 0.0f);
        }
    }
    // slots 4-7: c2 corners inside c1
    {
        float ax = c1x[0], ay = c1y[0];
        float abx = FSUB(c1x[1], ax), aby = FSUB(c1y[1], ay);
        float adx = FSUB(c1x[3], ax), ady = FSUB(c1y[3], ay);
        float rab = rcpf_(FADD(FMUL(abx, abx), FMUL(aby, aby)));
        float rad = rcpf_(FADD(FMUL(adx, adx), FMUL(ady, ady)));
#pragma unroll
        for (int j = 0; j < 4; j++) {
            float amx = FSUB(c2x[j], ax), amy = FSUB(c2y[j], ay);
            float pab = FMUL(FADD(FMUL(abx, amx), FMUL(aby, amy)), rab);
            float pad = FMUL(FADD(FMUL(adx, amx), FMUL(ady, amy)), rad);
            int m = (pab > -eps) & (pab < hieps) & (pad > -eps) & (pad < hieps);
            vx[4 + j] = c2x[j]; vy[4 + j] = c2y[j];
            mbits |= (unsigned)m << (4 + j);
            sx = FADD(sx, m ? c2x[j] : 0.0f);
            sy = FADD(sy, m ? c2y[j] : 0.0f);
        }
    }
    // slots 8-23: edge intersections; den_u = -den_t exactly -> one rcp.
    float fex[4], fey[4];
#pragma unroll
    for (int e2 = 0; e2 < 4; e2++) {
        fex[e2] = FSUB(c2x[(e2 + 1) & 3], c2x[e2]);
        fey[e2] = FSUB(c2y[(e2 + 1) & 3], c2y[e2]);
    }
#pragma unroll
    for (int e1 = 0; e1 < 4; e1++) {
        float x1 = c1x[e1], y1 = c1y[e1];
        float ex = FSUB(c1x[(e1 + 1) & 3], x1), ey = FSUB(c1y[(e1 + 1) & 3], y1);
#pragma unroll
        for (int e2 = 0; e2 < 4; e2++) {
            float dx31 = FSUB(c2x[e2], x1), dy31 = FSUB(c2y[e2], y1);
            float num_t = FSUB(FMUL(ex, dy31), FMUL(ey, dx31));
            float den_t = FSUB(FMUL(ey, fex[e2]), FMUL(ex, fey[e2]));
            float rd = rcpf_(den_t);          // den==0 -> inf -> masked below
            float tq = FMUL(num_t, rd);
            float num_u = FSUB(FMUL(fey[e2], dx31), FMUL(fex[e2], dy31));
            float uq = FMUL(num_u, rd);       // == -u exactly
            int m = (tq > 0.0f) & (tq < 1.0f) & (uq < 0.0f) & (uq > -1.0f);
            float ix = FADD(x1, FMUL(tq, ex));   // garbage if masked; gated
            float iy = FADD(y1, FMUL(tq, ey));
            int s = 8 + 4 * e1 + e2;
            vx[s] = ix; vy[s] = iy;
            mbits |= (unsigned)m << s;
            sx = FADD(sx, m ? ix : 0.0f);
            sy = FADD(sy, m ? iy : 0.0f);
        }
    }

    int k = __popc(mbits);

    // centroid (IEEE div: feeds every recentered coordinate — bit-frozen)
    float kk = (float)(k > 0 ? k : 1);
    float mx = FDIV(sx, kk), my = FDIV(sy, kk);

    // ---- phase 2: recenter + u32 packed keys (27-bit angle | 5-bit slot) ----
    // Masked slots keep garbage coords (never selected: when s<k a genuine
    // un-extracted key always beats masked; when s>=k payload gated to prev).
    unsigned pk[24];
#pragma unroll
    for (int j = 0; j < 24; j++) {
        int m = (mbits >> j) & 1u;
        float wx2 = FSUB(vx[j], mx);
        float wy2 = FSUB(vy[j], my);
        vx[j] = wx2; vy[j] = wy2;
        float dsum = FADD(fabsf(wx2), fabsf(wy2));
        float rs = (dsum > 0.0f) ? FMUL(wx2, rcpf_(dsum)) : 1.0f;
        float keyf = copysignf(FSUB(1.0f, rs), wy2);   // monotone in atan2
        unsigned sb = __float_as_uint(keyf);
        unsigned u = sb ^ (unsigned)(((int)sb >> 31) | (int)0x80000000);
        pk[j] = m ? ((u & 0xFFFFFFE0u) | (unsigned)j)
                  : (0xFFFFFFE0u | (unsigned)j);       // masked: sorts last
    }

    // ---- phase 3: rotation-based extract-min, 4 chains of 6 + combine ----
    unsigned prevkey = 0xFFFFFFFFu;   // poff = 0 on pass 0 -> w = pk
    float firstx = 0.0f, firsty = 0.0f, prevx = 0.0f, prevy = 0.0f;
    float crs = 0.0f;
#pragma unroll
    for (int s = 0; s < 8; s++) {
        unsigned poff = prevkey + 1u;
        unsigned cb0, cb1, cb2, cb3;
        float cxx0, cxx1, cxx2, cxx3, cyy0, cyy1, cyy2, cyy3;
#pragma unroll
        for (int c = 0; c < 4; c++) {
            unsigned b = pk[6 * c] - poff;
            float bx = vx[6 * c], by = vy[6 * c];
#pragma unroll
            for (int t = 1; t < 6; t++) {
                int j = 6 * c + t;
                unsigned wj = pk[j] - poff;
                bool lt = wj < b;
                b  = lt ? wj : b;
                bx = lt ? vx[j] : bx;
                by = lt ? vy[j] : by;
            }
            if (c == 0) { cb0 = b; cxx0 = bx; cyy0 = by; }
            else if (c == 1) { cb1 = b; cxx1 = bx; cyy1 = by; }
            else if (c == 2) { cb2 = b; cxx2 = bx; cyy2 = by; }
            else { cb3 = b; cxx3 = bx; cyy3 = by; }
        }
        bool l01 = cb1 < cb0;
        unsigned b01 = l01 ? cb1 : cb0;
        float x01 = l01 ? cxx1 : cxx0, y01 = l01 ? cyy1 : cyy0;
        bool l23 = cb3 < cb2;
        unsigned b23 = l23 ? cb3 : cb2;
        float x23 = l23 ? cxx3 : cxx2, y23 = l23 ? cyy3 : cyy2;
        bool lf = b23 < b01;
        unsigned bw = lf ? b23 : b01;
        float bx = lf ? x23 : x01, by = lf ? y23 : y01;
        unsigned bestkey = bw + poff;
        bool act = s < k;              // inactive pass: payload -> prev
        bx = act ? bx : prevx;
        by = act ? by : prevy;
        if (s == 0) { firstx = bx; firsty = by; }
        else {
            // inactive: cross(prev,prev) = exact IEEE 0 (identical products)
            crs = FADD(crs, FSUB(FMUL(prevx, by), FMUL(prevy, bx)));
        }
        prevx = bx; prevy = by; prevkey = bestkey;
    }
    // rare tail: noise masks can push k past the geometric bound of 8
    for (int s = 8; s < k; s++) {
        unsigned poff = prevkey + 1u;
        unsigned best = pk[0] - poff;
        float bx = vx[0], by = vy[0];
#pragma unroll
        for (int j = 1; j < 24; j++) {
            unsigned wj = pk[j] - poff;
            bool lt = wj < best;
            best = lt ? wj : best;
            bx = lt ? vx[j] : bx;
            by = lt ? vy[j] : by;
        }
        crs = FADD(crs, FSUB(FMUL(prevx, by), FMUL(prevy, bx)));
        prevx = bx; prevy = by; prevkey = best + poff;
    }
    // close the ring
    crs = FADD(crs, FSUB(FMUL(prevx, firsty), FMUL(prevy, firstx)));
    float inter = FMUL(0.5f, fabsf(crs));

    float area1 = FMUL(pw, ph), area2 = FMUL(qw, qh);
    float uni = FSUB(FADD(area1, area2), inter);
    float iou = FMUL(inter, rcpf_(uni));

    out[i] = FADD(FSUB(1.0f, iou), FMUL(d2, rcpf_(c2d)));
}

extern "C" void kernel_launch(void* const* d_in, const int* in_sizes, int n_in,
                              void* d_out, int out_size, void* d_ws, size_t ws_size,
                              hipStream_t stream) {
    const float* pred = (const float*)d_in[0];
    const float* tgt  = (const float*)d_in[1];
    float* out = (float*)d_out;
    int n = in_sizes[0] / 6;
    int block = 256;
    int grid = (n + block - 1) / block;
    riou_kernel<<<grid, block, 0, stream>>>(pred, tgt, out, n);
}